// Round 3
// baseline (549.400 us; speedup 1.0000x reference)
//
#include <hip/hip_runtime.h>

// Problem constants (from reference setup_inputs)
#define BB 32
#define NUM_EXO 8
#define HW 784
#define CC 512
#define HH 28
#define WW 28
#define EXO_ROWS (BB * NUM_EXO * HW)   // 200704
#define EGO_ROWS (BB * HW)             // 25088
#define EPSV 1e-12f

__device__ __forceinline__ float wave_reduce_sum(float v) {
#pragma unroll
    for (int m = 32; m >= 1; m >>= 1)
        v += __shfl_xor(v, m, 64);
    return v;
}

// Kernel A: normalize the two (32, 512) vectors into workspace.
// One wave per row; 64 rows total.
__global__ __launch_bounds__(256) void norm_vecs_kernel(
    const float* __restrict__ aff, const float* __restrict__ txt,
    float* __restrict__ aff_n, float* __restrict__ txt_n) {
    int wave = (int)((blockIdx.x * blockDim.x + threadIdx.x) >> 6);
    int lane = threadIdx.x & 63;
    if (wave >= 2 * BB) return;
    const float* src = (wave < BB) ? aff + (size_t)wave * CC : txt + (size_t)(wave - BB) * CC;
    float*       dst = (wave < BB) ? aff_n + (size_t)wave * CC : txt_n + (size_t)(wave - BB) * CC;
    const float4* s4 = reinterpret_cast<const float4*>(src);
    float4 v0 = s4[lane];
    float4 v1 = s4[lane + 64];
    float ss = v0.x * v0.x + v0.y * v0.y + v0.z * v0.z + v0.w * v0.w
             + v1.x * v1.x + v1.y * v1.y + v1.z * v1.z + v1.w * v1.w;
    ss = wave_reduce_sum(ss);
    float inv = 1.0f / fmaxf(sqrtf(ss), EPSV);
    float4* d4 = reinterpret_cast<float4*>(dst);
    float4 o0 = {v0.x * inv, v0.y * inv, v0.z * inv, v0.w * inv};
    float4 o1 = {v1.x * inv, v1.y * inv, v1.z * inv, v1.w * inv};
    d4[lane] = o0;
    d4[lane + 64] = o1;
}

// Kernel B: one wave per 512-float row. Rows [0, EXO_ROWS): exo rows
// (dot with txt_n and aff_n, divided by row norm). Rows
// [EXO_ROWS, EXO_ROWS+EGO_ROWS): ego rows (dot with aff_n only).
// sim_obj -> ws; sim_aff -> out[EGO_ROWS + r] (staged, multiplied later);
// ego similarity -> out[r].
__global__ __launch_bounds__(256) void row_dots_kernel(
    const float* __restrict__ exo, const float* __restrict__ ego,
    const float* __restrict__ aff_n, const float* __restrict__ txt_n,
    float* __restrict__ sim_obj, float* __restrict__ out) {
    long wave = ((long)blockIdx.x * blockDim.x + threadIdx.x) >> 6;
    int lane = threadIdx.x & 63;
    if (wave >= (long)(EXO_ROWS + EGO_ROWS)) return;

    if (wave < EXO_ROWS) {
        int r = (int)wave;
        int b = r / (NUM_EXO * HW);
        const float4* x4 = reinterpret_cast<const float4*>(exo + (size_t)r * CC);
        const float4* a4 = reinterpret_cast<const float4*>(aff_n + (size_t)b * CC);
        const float4* t4 = reinterpret_cast<const float4*>(txt_n + (size_t)b * CC);
        float ss = 0.f, da = 0.f, dt = 0.f;
#pragma unroll
        for (int k = 0; k < 2; ++k) {
            float4 v = x4[lane + 64 * k];
            float4 a = a4[lane + 64 * k];
            float4 t = t4[lane + 64 * k];
            ss += v.x * v.x + v.y * v.y + v.z * v.z + v.w * v.w;
            da += v.x * a.x + v.y * a.y + v.z * a.z + v.w * a.w;
            dt += v.x * t.x + v.y * t.y + v.z * t.z + v.w * t.w;
        }
        ss = wave_reduce_sum(ss);
        da = wave_reduce_sum(da);
        dt = wave_reduce_sum(dt);
        if (lane == 0) {
            float inv = 1.0f / fmaxf(sqrtf(ss), EPSV);
            sim_obj[r] = dt * inv;
            out[EGO_ROWS + r] = da * inv;  // staged sim_aff
        }
    } else {
        int r = (int)(wave - EXO_ROWS);
        int b = r / HW;
        const float4* x4 = reinterpret_cast<const float4*>(ego + (size_t)r * CC);
        const float4* a4 = reinterpret_cast<const float4*>(aff_n + (size_t)b * CC);
        float ss = 0.f, da = 0.f;
#pragma unroll
        for (int k = 0; k < 2; ++k) {
            float4 v = x4[lane + 64 * k];
            float4 a = a4[lane + 64 * k];
            ss += v.x * v.x + v.y * v.y + v.z * v.z + v.w * v.w;
            da += v.x * a.x + v.y * a.y + v.z * a.z + v.w * a.w;
        }
        ss = wave_reduce_sum(ss);
        da = wave_reduce_sum(da);
        if (lane == 0) {
            out[r] = da / fmaxf(sqrtf(ss), EPSV);
        }
    }
}

// Kernel C: edge-aware 3x3 box mean of sim_obj, times staged sim_aff.
__global__ __launch_bounds__(256) void box_mul_kernel(
    const float* __restrict__ sim_obj, float* __restrict__ out) {
    int e = blockIdx.x * blockDim.x + threadIdx.x;
    if (e >= EXO_ROWS) return;
    int x = e % WW;
    int y = (e / WW) % HH;
    int base = e - y * WW - x;  // start of this (b, n) 28x28 map
    float s = 0.f;
    int cnt = 0;
#pragma unroll
    for (int dy = -1; dy <= 1; ++dy) {
        int yy = y + dy;
        if (yy < 0 || yy >= HH) continue;
#pragma unroll
        for (int dx = -1; dx <= 1; ++dx) {
            int xx = x + dx;
            if (xx < 0 || xx >= WW) continue;
            s += sim_obj[base + yy * WW + xx];
            ++cnt;
        }
    }
    out[EGO_ROWS + e] = (s / (float)cnt) * out[EGO_ROWS + e];
}

extern "C" void kernel_launch(void* const* d_in, const int* in_sizes, int n_in,
                              void* d_out, int out_size, void* d_ws, size_t ws_size,
                              hipStream_t stream) {
    const float* exo = (const float*)d_in[0];  // (256, 784, 512)
    const float* ego = (const float*)d_in[1];  // (32, 784, 512)
    const float* aff = (const float*)d_in[2];  // (32, 512)
    const float* txt = (const float*)d_in[3];  // (32, 512)
    float* out = (float*)d_out;                // [ego_sim (25088) | exo_sim_neighbor (200704)]
    float* ws = (float*)d_ws;

    float* aff_n   = ws;                  // 32*512
    float* txt_n   = ws + BB * CC;        // 32*512
    float* sim_obj = ws + 2 * BB * CC;    // 200704

    // A: normalize the two small vector sets (64 waves -> 16 blocks).
    norm_vecs_kernel<<<16, 256, 0, stream>>>(aff, txt, aff_n, txt_n);

    // B: one wave per row; 4 waves per 256-thread block.
    long total_waves = (long)EXO_ROWS + EGO_ROWS;  // 225792
    int blocks = (int)((total_waves + 3) / 4);     // 56448
    row_dots_kernel<<<blocks, 256, 0, stream>>>(exo, ego, aff_n, txt_n, sim_obj, out);

    // C: box filter + multiply (tiny).
    box_mul_kernel<<<(EXO_ROWS + 255) / 256, 256, 0, stream>>>(sim_obj, out);
}